// Round 1
// baseline (450.354 us; speedup 1.0000x reference)
//
#include <hip/hip_runtime.h>

// Holt double-exponential smoothing along T for x[B=32, T=4096, C=512] fp32.
//   s[0] = x[0]; b[0] = x[1] - x[0]
//   s[t] = a*x[t] + (1-a)*(s[t-1] + b[t-1])
//   b[t] = B*(s[t] - s[t-1]) + (1-B)*b[t-1]
// out[t] = s[t].
//
// Parallel-in-T via chunked warm-up restart: transition matrix spectral
// radius ~0.785 -> 64 warm-up steps reduce restart error by ~2e-7.

#define ALPHA 0.8f
#define BETA 0.2f

constexpr int T = 4096;
constexpr int C = 512;
constexpr int C2 = C / 2;       // float2 columns per (b,t) row
constexpr int CHUNK = 256;      // output timesteps per chunk
constexpr int WARM = 64;        // warm-up timesteps (error ~0.785^63 ~ 2e-7)
constexpr int NCHUNK = T / CHUNK;

__device__ __forceinline__ void holt_step(float xi, float& s, float& b) {
    float s_new = ALPHA * xi + (1.0f - ALPHA) * (s + b);
    b = BETA * (s_new - s) + (1.0f - BETA) * b;
    s = s_new;
}

__global__ __launch_bounds__(256) void holt_kernel(const float* __restrict__ x,
                                                   float* __restrict__ out) {
    const int c2 = threadIdx.x;        // 0..255 (float2 column)
    const int chunk = blockIdx.x;      // 0..NCHUNK-1
    const int b = blockIdx.y;          // 0..31

    const int t0 = chunk * CHUNK;
    const int tw = (chunk == 0) ? 0 : t0 - WARM;

    const float2* __restrict__ xin =
        reinterpret_cast<const float2*>(x) + (size_t)b * T * C2 + c2;
    float2* __restrict__ o =
        reinterpret_cast<float2*>(out) + (size_t)b * T * C2 + c2;

    // Init state at t = tw (exact for chunk 0, cold restart otherwise).
    float2 x0 = xin[(size_t)tw * C2];
    float2 x1 = xin[(size_t)(tw + 1) * C2];
    float sx = x0.x, sy = x0.y;
    float bx = x1.x - x0.x, by = x1.y - x0.y;

    if (chunk == 0) {
        o[0] = make_float2(sx, sy);   // out[0] = s[0] = x[0]
    } else {
        // Warm-up: t = tw+1 .. t0-1, no stores.
        #pragma unroll 4
        for (int t = tw + 1; t < t0; ++t) {
            float2 xi = xin[(size_t)t * C2];
            holt_step(xi.x, sx, bx);
            holt_step(xi.y, sy, by);
        }
    }

    // Main loop: compute + store.
    const int tstart = (chunk == 0) ? 1 : t0;
    #pragma unroll 4
    for (int t = tstart; t < t0 + CHUNK; ++t) {
        float2 xi = xin[(size_t)t * C2];
        holt_step(xi.x, sx, bx);
        holt_step(xi.y, sy, by);
        o[(size_t)t * C2] = make_float2(sx, sy);
    }
}

extern "C" void kernel_launch(void* const* d_in, const int* in_sizes, int n_in,
                              void* d_out, int out_size, void* d_ws, size_t ws_size,
                              hipStream_t stream) {
    const float* x = (const float*)d_in[0];
    float* out = (float*)d_out;
    dim3 grid(NCHUNK, 32);   // 16 chunks x 32 batches = 512 blocks, 4 waves each
    holt_kernel<<<grid, 256, 0, stream>>>(x, out);
}

// Round 2
// 449.863 us; speedup vs baseline: 1.0011x; 1.0011x over previous
//
#include <hip/hip_runtime.h>

// Holt double-exponential smoothing along T for x[B=32, T=4096, C=512] fp32.
//   s[0] = x[0]; b[0] = x[1] - x[0]
//   s[t] = a*x[t] + (1-a)*(s[t-1] + b[t-1])
//   b[t] = B*(s[t] - s[t-1]) + (1-B)*b[t-1]
// out[t] = s[t].
//
// Parallel-in-T via chunked warm-up restart (transition spectral radius
// ~0.785 -> 64 warm-up steps shrink restart error by ~2e-7).
//
// R2: explicit depth-8 register load pipeline. Loads are independent of the
// recurrence state; consuming buf[i&7] in order keeps 8 loads in flight per
// wave (s_waitcnt vmcnt(7) pattern) instead of draining per unroll block.
// NITER padded to a multiple of 8 for ALL chunks so the unrolled buf indices
// stay static (no scratch spill); store guards are block-uniform.

#define ALPHA 0.8f
#define BETA 0.2f

constexpr int T = 4096;
constexpr int C = 512;
constexpr int C2 = C / 2;       // float2 columns per (b,t) row
constexpr int CHUNK = 256;      // output timesteps per chunk
constexpr int WARM = 64;        // warm-up timesteps
constexpr int NCHUNK = T / CHUNK;   // 16
constexpr int P = 8;            // load pipeline depth (power of 2)
constexpr int NITER = CHUNK + WARM; // 320, multiple of 8, uniform all chunks

__device__ __forceinline__ void holt_step(float xi, float& s, float& b) {
    float s_new = ALPHA * xi + (1.0f - ALPHA) * (s + b);
    b = BETA * (s_new - s) + (1.0f - BETA) * b;
    s = s_new;
}

__global__ __launch_bounds__(256) void holt_kernel(const float* __restrict__ x,
                                                   float* __restrict__ out) {
    const int c2 = threadIdx.x;        // 0..255 (float2 column)
    const int chunk = blockIdx.x;      // 0..NCHUNK-1
    const int b = blockIdx.y;          // 0..31

    const int t0 = chunk * CHUNK;
    const int tw = (chunk == 0) ? 0 : t0 - WARM;   // state-init timestep

    const float2* __restrict__ xin =
        reinterpret_cast<const float2*>(x) + (size_t)b * T * C2 + c2;
    float2* __restrict__ o =
        reinterpret_cast<float2*>(out) + (size_t)b * T * C2 + c2;

    // Init state at t = tw (exact for chunk 0, cold restart otherwise).
    float2 x0 = xin[(size_t)tw * C2];
    float2 x1 = xin[(size_t)(tw + 1) * C2];
    float sx = x0.x, sy = x0.y;
    float bx = x1.x - x0.x, by = x1.y - x0.y;

    if (chunk == 0) {
        o[0] = make_float2(sx, sy);   // out[0] = s[0] = x[0]
    }

    const int t_start = tw + 1;       // first timestep consumed by the loop
    const int t_hi = t0 + CHUNK;      // store iff t0 <= t < t_hi

    // Prime the pipeline.
    float2 buf[P];
#pragma unroll
    for (int j = 0; j < P; ++j) {
        int t = t_start + j;
        t = (t < T) ? t : (T - 1);    // clamp (uniform, always in-bounds)
        buf[j] = xin[(size_t)t * C2];
    }

#pragma unroll 8
    for (int i = 0; i < NITER; ++i) {
        float2 xi = buf[i & (P - 1)];
        // Prefetch t + P into the slot just freed (clamped address so the
        // load is unconditional -> pipeline depth stays constant).
        int tp = t_start + i + P;
        tp = (tp < T) ? tp : (T - 1);
        buf[i & (P - 1)] = xin[(size_t)tp * C2];

        holt_step(xi.x, sx, bx);
        holt_step(xi.y, sy, by);

        const int t = t_start + i;    // block-uniform
        if (t >= t0 && t < t_hi) {
            o[(size_t)t * C2] = make_float2(sx, sy);
        }
    }
}

extern "C" void kernel_launch(void* const* d_in, const int* in_sizes, int n_in,
                              void* d_out, int out_size, void* d_ws, size_t ws_size,
                              hipStream_t stream) {
    const float* x = (const float*)d_in[0];
    float* out = (float*)d_out;
    dim3 grid(NCHUNK, 32);   // 16 chunks x 32 batches = 512 blocks, 4 waves each
    holt_kernel<<<grid, 256, 0, stream>>>(x, out);
}